// Round 8
// baseline (208.680 us; speedup 1.0000x reference)
//
#include <hip/hip_runtime.h>
#include <cstdint>
#include <cstddef>

#define N_SEQ 4096
#define D_HEAD 128
#define KP_DIM 256

typedef __attribute__((ext_vector_type(4))) float f32x4;
typedef __attribute__((ext_vector_type(8))) short bf16x8;
typedef __attribute__((ext_vector_type(4))) short s16x4;
typedef __attribute__((ext_vector_type(2))) unsigned int u32x2;

static __device__ __forceinline__ short f2bf(float f) {
  uint32_t u = __builtin_bit_cast(uint32_t, f);
  u += 0x7FFFu + ((u >> 16) & 1u);
  return (short)(u >> 16);
}

static __device__ __forceinline__ unsigned int cvtpk(float a, float b) {
  unsigned int r;
  asm("v_cvt_pk_bf16_f32 %0, %1, %2" : "=v"(r) : "v"(a), "v"(b));
  return r;
}

static __device__ __forceinline__ int swz8(int r) { return (r ^ (r >> 2)) & 7; }

// ---------------------------------------------------------------------------
// Stage 0: convert E_W,F_W f32 -> bf16 wbf[2][256][4096] (d_out scratch)
// ---------------------------------------------------------------------------
__global__ __launch_bounds__(256) void conv_w_kernel(
    const float* __restrict__ EW, const float* __restrict__ FW,
    short* __restrict__ wbf) {
  const int idx = blockIdx.x * 256 + threadIdx.x;
  const int half = 262144;
  f32x4 v = (idx < half) ? *(const f32x4*)(EW + (size_t)idx * 4)
                         : *(const f32x4*)(FW + (size_t)(idx - half) * 4);
  u32x2 h = {cvtpk(v[0], v[1]), cvtpk(v[2], v[3])};
  *(u32x2*)(wbf + (size_t)idx * 4) = h;
}

// ---------------------------------------------------------------------------
// Stage 1: partial projections (unchanged). grid 256, 512 thr.
// ---------------------------------------------------------------------------
__global__ __launch_bounds__(512) void proj_partial_kernel(
    const float* __restrict__ Kin, const float* __restrict__ Vin,
    const short* __restrict__ wbf, float* __restrict__ pws) {
  const int bid = blockIdx.x;
  const int wk = (bid & 7) * 32 + (bid >> 3);
  const int b = wk & 31;
  const int s = (wk >> 5) & 3;
  const int p = wk >> 7;

  const float* __restrict__ X = (p == 0 ? Kin : Vin) + (size_t)b * (N_SEQ * D_HEAD);
  const short* __restrict__ wp = wbf + (size_t)p * (KP_DIM * N_SEQ);
  float* __restrict__ outp = pws + ((((size_t)b * 2 + p) * 4) + s) * (KP_DIM * D_HEAD);

  __shared__ __align__(16) short lw[2][KP_DIM * 64];
  __shared__ __align__(16) short xt[2][D_HEAD * 64];

  const int t = threadIdx.x;
  const int lane = t & 63;
  const int w = t >> 6;
  const int wm = (w >> 1) * 64;
  const int wn = (w & 1) * 64;
  const int l15 = lane & 15;
  const int l4 = lane >> 4;
  const int dq = t & 31;
  const int ng = t >> 5;

  const int n0 = s * 1024;

  f32x4 acc[4][4];
#pragma unroll
  for (int i = 0; i < 4; ++i)
#pragma unroll
    for (int j = 0; j < 4; ++j) acc[i][j] = (f32x4){0.f, 0.f, 0.f, 0.f};

  f32x4 xreg[4];

#pragma unroll
  for (int i = 0; i < 4; ++i)
    xreg[i] = *(const f32x4*)(X + (size_t)(n0 + ng * 4 + i) * D_HEAD + dq * 4);
#pragma unroll
  for (int i = 0; i < 4; ++i) {
    int g = t + i * 512;
    int row = g >> 3, c = g & 7;
    __builtin_amdgcn_global_load_lds(
        (const __attribute__((address_space(1))) void*)(wp + (size_t)row * N_SEQ + n0 +
                                                        ((c ^ swz8(row)) << 3)),
        (__attribute__((address_space(3))) void*)(&lw[0][g * 8]), 16, 0, 0);
  }
  asm volatile("s_waitcnt vmcnt(4)" ::: "memory");
#pragma unroll
  for (int j = 0; j < 4; ++j) {
    int drow = dq * 4 + j;
    u32x2 hv = {cvtpk(xreg[0][j], xreg[1][j]), cvtpk(xreg[2][j], xreg[3][j])};
    *(u32x2*)(&xt[0][drow * 64 + ((ng * 4) ^ (swz8(drow) << 3))]) = hv;
  }
  asm volatile("s_waitcnt vmcnt(0)" ::: "memory");
  __syncthreads();

  for (int it = 0; it < 16; ++it) {
    const int cur = it & 1, nxt = cur ^ 1;
    if (it < 15) {
      const int nc = n0 + (it + 1) * 64;
#pragma unroll
      for (int i = 0; i < 4; ++i)
        xreg[i] = *(const f32x4*)(X + (size_t)(nc + ng * 4 + i) * D_HEAD + dq * 4);
#pragma unroll
      for (int i = 0; i < 4; ++i) {
        int g = t + i * 512;
        int row = g >> 3, c = g & 7;
        __builtin_amdgcn_global_load_lds(
            (const __attribute__((address_space(1))) void*)(wp + (size_t)row * N_SEQ + nc +
                                                            ((c ^ swz8(row)) << 3)),
            (__attribute__((address_space(3))) void*)(&lw[nxt][g * 8]), 16, 0, 0);
      }
    }
#pragma unroll
    for (int ks2 = 0; ks2 < 2; ++ks2) {
      const int col0 = ks2 * 32 + l4 * 8;
      bf16x8 a[4], bb[4];
#pragma unroll
      for (int mt = 0; mt < 4; ++mt) {
        int row = wm + mt * 16 + l15;
        a[mt] = *(const bf16x8*)(&lw[cur][row * 64 + (col0 ^ (swz8(row) << 3))]);
      }
#pragma unroll
      for (int nt = 0; nt < 4; ++nt) {
        int row = wn + nt * 16 + l15;
        bb[nt] = *(const bf16x8*)(&xt[cur][row * 64 + (col0 ^ (swz8(row) << 3))]);
      }
#pragma unroll
      for (int mt = 0; mt < 4; ++mt)
#pragma unroll
        for (int nt = 0; nt < 4; ++nt)
          acc[mt][nt] = __builtin_amdgcn_mfma_f32_16x16x32_bf16(a[mt], bb[nt], acc[mt][nt], 0, 0, 0);
    }
    if (it < 15) {
      asm volatile("s_waitcnt vmcnt(4)" ::: "memory");
#pragma unroll
      for (int j = 0; j < 4; ++j) {
        int drow = dq * 4 + j;
        u32x2 hv = {cvtpk(xreg[0][j], xreg[1][j]), cvtpk(xreg[2][j], xreg[3][j])};
        *(u32x2*)(&xt[nxt][drow * 64 + ((ng * 4) ^ (swz8(drow) << 3))]) = hv;
      }
      asm volatile("s_waitcnt vmcnt(0)" ::: "memory");
    }
    __syncthreads();
  }

#pragma unroll
  for (int mt = 0; mt < 4; ++mt)
#pragma unroll
    for (int nt = 0; nt < 4; ++nt)
#pragma unroll
      for (int r = 0; r < 4; ++r) {
        int kk = wm + mt * 16 + l4 * 4 + r;
        int dd = wn + nt * 16 + l15;
        outp[kk * D_HEAD + dd] = acc[mt][nt][r];
      }
}

// ---------------------------------------------------------------------------
// Stage 1b: reduce 4 partials + bias. grid 128.
// ---------------------------------------------------------------------------
__global__ __launch_bounds__(256) void reduce_bias_kernel(
    const float* __restrict__ pws, const float* __restrict__ Eb,
    const float* __restrict__ Fb, short* __restrict__ kp, short* __restrict__ vpt) {
  const int sub = blockIdx.x & 3;
  const int b = blockIdx.x >> 2;
  const int t = threadIdx.x;
  __shared__ short tile[128 * 128];
  if (sub < 2) {
    const float* __restrict__ base = pws + ((size_t)b * 2) * 4 * 32768;
    const int off = sub * 16384;
    for (int i = t; i < 16384; i += 256) {
      int ii = off + i;
      int k = ii >> 7;
      float v = base[ii] + base[ii + 32768] + base[ii + 65536] + base[ii + 98304] + Eb[k];
      kp[(size_t)b * 32768 + ii] = f2bf(v);
    }
  } else {
    const int kh = sub - 2;
    const float* __restrict__ base = pws + (((size_t)b * 2 + 1) * 4) * 32768 + kh * 16384;
    for (int i = t; i < 16384; i += 256) {
      int kl = i >> 7, d = i & 127;
      float v = base[i] + base[i + 32768] + base[i + 65536] + base[i + 98304] + Fb[kh * 128 + kl];
      tile[kl * 128 + (d ^ ((kl & 15) << 3))] = f2bf(v);
    }
    __syncthreads();
    for (int i = t; i < 16384; i += 256) {
      int d = i >> 7, kl = i & 127;
      vpt[(size_t)b * 32768 + d * 256 + kh * 128 + kl] = tile[kl * 128 + (d ^ ((kl & 15) << 3))];
    }
  }
}

// ---------------------------------------------------------------------------
// Stage 2: attention v3. grid 256 (XCD-chunked), 1024 thr = 16 waves
// (4 waves/SIMD). One 32-row round per wave (A/B row-group pairing shares
// every kp/vpt LDS fragment read across 2 MFMAs). LDS 128KB: kp + vpt; the
// P-transpose scratch ALIASES kp's 64KB (kp dead after QK^T; one barrier).
// PV computed transposed (mfma(av,pa)) so lanes store f32x4 (coalesced).
// ---------------------------------------------------------------------------
__global__ __launch_bounds__(1024) void attn_kernel(
    const float* __restrict__ Q, const short* __restrict__ kp,
    const short* __restrict__ vpt, float* __restrict__ out) {
  const int bid = blockIdx.x;
  const int wk = (bid & 7) * 32 + (bid >> 3);  // XCD-chunked: 4 b's per XCD
  const int b = wk >> 3;
  const int slice = wk & 7;
  const int t = threadIdx.x;
  const int lane = t & 63;
  const int w = t >> 6;  // 0..15
  const int l15 = lane & 15, l4 = lane >> 4;

  // 128KB LDS: lkp 64KB (later reused as P scratch), lvpt 64KB
  __shared__ __align__(16) short lbuf[65536];
  short* lkp = lbuf;            // kp[k][d] swizzled
  short* lvpt = lbuf + 32768;   // vpt[d][k] swizzled

  const short* __restrict__ kpb = kp + (size_t)b * 32768;
  const short* __restrict__ vptb = vpt + (size_t)b * 32768;

  // ---- stage kp + vpt (linear LDS dest, swizzled source) ----
#pragma unroll
  for (int i = 0; i < 4; ++i) {
    int g = t + i * 1024;              // 16B chunk 0..4095
    int row = g >> 4, c = g & 15;
    __builtin_amdgcn_global_load_lds(
        (const __attribute__((address_space(1))) void*)(kpb + (size_t)row * 128 +
                                                        ((c ^ (row & 7)) << 3)),
        (__attribute__((address_space(3))) void*)(&lkp[g * 8]), 16, 0, 0);
  }
#pragma unroll
  for (int i = 0; i < 4; ++i) {
    int g = t + i * 1024;
    int row = g >> 5, c = g & 31;
    __builtin_amdgcn_global_load_lds(
        (const __attribute__((address_space(1))) void*)(vptb + (size_t)row * 256 +
                                                        ((c ^ (row & 7)) << 3)),
        (__attribute__((address_space(3))) void*)(&lvpt[g * 8]), 16, 0, 0);
  }

  // ---- Q loads issued under the staging DMA (one vmcnt drain) ----
  const int rowBase = slice * 512 + w * 32;
  const float scale = 0.08838834764831845f;  // 1/sqrt(128)
  f32x4 qta[8], qtb[8];
  {
    const float* qra = Q + ((size_t)b * N_SEQ + rowBase + l15) * D_HEAD;
    const float* qrb = qra + 16 * D_HEAD;
#pragma unroll
    for (int ks = 0; ks < 4; ++ks) {
      qta[2 * ks] = *(const f32x4*)(qra + ks * 32 + l4 * 8);
      qta[2 * ks + 1] = *(const f32x4*)(qra + ks * 32 + l4 * 8 + 4);
      qtb[2 * ks] = *(const f32x4*)(qrb + ks * 32 + l4 * 8);
      qtb[2 * ks + 1] = *(const f32x4*)(qrb + ks * 32 + l4 * 8 + 4);
    }
  }
  asm volatile("s_waitcnt vmcnt(0)" ::: "memory");

  bf16x8 qfA[4], qfB[4];
#pragma unroll
  for (int ks = 0; ks < 4; ++ks) {
    union { unsigned int u[4]; bf16x8 v; } ca, cb;
    ca.u[0] = cvtpk(qta[2 * ks][0] * scale, qta[2 * ks][1] * scale);
    ca.u[1] = cvtpk(qta[2 * ks][2] * scale, qta[2 * ks][3] * scale);
    ca.u[2] = cvtpk(qta[2 * ks + 1][0] * scale, qta[2 * ks + 1][1] * scale);
    ca.u[3] = cvtpk(qta[2 * ks + 1][2] * scale, qta[2 * ks + 1][3] * scale);
    qfA[ks] = ca.v;
    cb.u[0] = cvtpk(qtb[2 * ks][0] * scale, qtb[2 * ks][1] * scale);
    cb.u[1] = cvtpk(qtb[2 * ks][2] * scale, qtb[2 * ks][3] * scale);
    cb.u[2] = cvtpk(qtb[2 * ks + 1][0] * scale, qtb[2 * ks + 1][1] * scale);
    cb.u[3] = cvtpk(qtb[2 * ks + 1][2] * scale, qtb[2 * ks + 1][3] * scale);
    qfB[ks] = cb.v;
  }
  __syncthreads();

  // ---- QK^T: shared af read feeds both row-groups ----
  f32x4 accsA[16], accsB[16];
#pragma unroll
  for (int i = 0; i < 16; ++i) {
    accsA[i] = (f32x4){0.f, 0.f, 0.f, 0.f};
    accsB[i] = (f32x4){0.f, 0.f, 0.f, 0.f};
  }
#pragma unroll
  for (int ks = 0; ks < 4; ++ks) {
#pragma unroll
    for (int nt = 0; nt < 16; ++nt) {
      bf16x8 af = *(const bf16x8*)(&lkp[(nt * 16 + l15) * 128 +
                                        (((ks * 4 + l4) ^ (l15 & 7)) << 3)]);
      accsA[nt] = __builtin_amdgcn_mfma_f32_16x16x32_bf16(af, qfA[ks], accsA[nt], 0, 0, 0);
      accsB[nt] = __builtin_amdgcn_mfma_f32_16x16x32_bf16(af, qfB[ks], accsB[nt], 0, 0, 0);
    }
  }

  // ---- softmax (lane owns one q-row; 2 shuffles per group) ----
  float mA = -1e30f, mB = -1e30f;
#pragma unroll
  for (int nt = 0; nt < 16; ++nt)
#pragma unroll
    for (int r = 0; r < 4; ++r) {
      mA = fmaxf(mA, accsA[nt][r]);
      mB = fmaxf(mB, accsB[nt][r]);
    }
  mA = fmaxf(mA, __shfl_xor(mA, 16)); mA = fmaxf(mA, __shfl_xor(mA, 32));
  mB = fmaxf(mB, __shfl_xor(mB, 16)); mB = fmaxf(mB, __shfl_xor(mB, 32));
  float sA = 0.f, sB = 0.f;
#pragma unroll
  for (int nt = 0; nt < 16; ++nt)
#pragma unroll
    for (int r = 0; r < 4; ++r) {
      float eA = __expf(accsA[nt][r] - mA);
      float eB = __expf(accsB[nt][r] - mB);
      accsA[nt][r] = eA; accsB[nt][r] = eB;
      sA += eA; sB += eB;
    }
  sA += __shfl_xor(sA, 16); sA += __shfl_xor(sA, 32);
  sB += __shfl_xor(sB, 16); sB += __shfl_xor(sB, 32);
  float invA = 1.0f / sA, invB = 1.0f / sB;

  // ---- all waves done with lkp: its 64KB becomes per-wave P scratch ----
  __syncthreads();
  short* lpw = lbuf + w * 2048;  // 4KB per wave: 32 rows x 128B (qq-quarter)

  f32x4 accoA[8], accoB[8];
#pragma unroll
  for (int i = 0; i < 8; ++i) {
    accoA[i] = (f32x4){0.f, 0.f, 0.f, 0.f};
    accoB[i] = (f32x4){0.f, 0.f, 0.f, 0.f};
  }
#pragma unroll
  for (int qq = 0; qq < 4; ++qq) {
#pragma unroll
    for (int ntl = 0; ntl < 4; ++ntl) {
      int nt = qq * 4 + ntl;
      int cw = 2 * ntl + (l4 >> 1);
      unsigned int a0 = cvtpk(accsA[nt][0] * invA, accsA[nt][1] * invA);
      unsigned int a1 = cvtpk(accsA[nt][2] * invA, accsA[nt][3] * invA);
      *(u32x2*)((char*)lpw + l15 * 128 + ((cw ^ (l15 & 7)) << 4) + (l4 & 1) * 8) =
          (u32x2){a0, a1};
      unsigned int b0 = cvtpk(accsB[nt][0] * invB, accsB[nt][1] * invB);
      unsigned int b1 = cvtpk(accsB[nt][2] * invB, accsB[nt][3] * invB);
      *(u32x2*)((char*)lpw + (16 + l15) * 128 + ((cw ^ (l15 & 7)) << 4) + (l4 & 1) * 8) =
          (u32x2){b0, b1};
    }
#pragma unroll
    for (int ksl = 0; ksl < 2; ++ksl) {
      // pa = P^T B-fragment (col = q-row = l15, k-chunk = l4*8)
      bf16x8 paA = *(const bf16x8*)((char*)lpw + l15 * 128 +
                                    (((4 * ksl + l4) ^ (l15 & 7)) << 4));
      bf16x8 paB = *(const bf16x8*)((char*)lpw + (16 + l15) * 128 +
                                    (((4 * ksl + l4) ^ (l15 & 7)) << 4));
      int ksa = qq * 2 + ksl;
#pragma unroll
      for (int ntv = 0; ntv < 8; ++ntv) {
        // av = VP^T A-fragment (row = d = ntv*16+l15, k = ksa*32 + l4*8)
        bf16x8 av = *(const bf16x8*)(&lvpt[(ntv * 16 + l15) * 256 +
                                           (((ksa * 4 + l4) ^ (l15 & 7)) << 3)]);
        // D = VP^T * P^T = out^T tile: row = d (l4*4+r consecutive), col = n
        accoA[ntv] = __builtin_amdgcn_mfma_f32_16x16x32_bf16(av, paA, accoA[ntv], 0, 0, 0);
        accoB[ntv] = __builtin_amdgcn_mfma_f32_16x16x32_bf16(av, paB, accoB[ntv], 0, 0, 0);
      }
    }
  }

  // ---- coalesced f32x4 stores: lane writes 4 consecutive d ----
  float* obA = out + ((size_t)b * N_SEQ + rowBase) * D_HEAD;
  float* obB = obA + 16 * D_HEAD;
#pragma unroll
  for (int ntv = 0; ntv < 8; ++ntv) {
    *(f32x4*)(obA + (size_t)l15 * D_HEAD + ntv * 16 + l4 * 4) = accoA[ntv];
    *(f32x4*)(obB + (size_t)l15 * D_HEAD + ntv * 16 + l4 * 4) = accoB[ntv];
  }
}

// ---------------------------------------------------------------------------
extern "C" void kernel_launch(void* const* d_in, const int* in_sizes, int n_in,
                              void* d_out, int out_size, void* d_ws, size_t ws_size,
                              hipStream_t stream) {
  const float* Q  = (const float*)d_in[0];
  const float* K  = (const float*)d_in[1];
  const float* V  = (const float*)d_in[2];
  const float* EW = (const float*)d_in[3];
  const float* Eb = (const float*)d_in[4];
  const float* FW = (const float*)d_in[5];
  const float* Fb = (const float*)d_in[6];
  float* out = (float*)d_out;

  // d_out scratch (dead before attn writes): [0,4MB) wbf; [8MB,41.5MB) pws
  short* wbf = (short*)d_out;
  float* pws = (float*)d_out + 2097152;
  short* kpb = (short*)d_ws;
  short* vpt = (short*)((char*)d_ws + (size_t)32 * KP_DIM * D_HEAD * 2);

  conv_w_kernel<<<dim3(2048), dim3(256), 0, stream>>>(EW, FW, wbf);
  proj_partial_kernel<<<dim3(256), dim3(512), 0, stream>>>(K, V, wbf, pws);
  reduce_bias_kernel<<<dim3(128), dim3(256), 0, stream>>>(pws, Eb, Fb, kpb, vpt);
  attn_kernel<<<dim3(256), dim3(1024), 0, stream>>>(Q, kpb, vpt, out);
}

// Round 9
// 97.531 us; speedup vs baseline: 2.1396x; 2.1396x over previous
//
#include <hip/hip_runtime.h>
#include <cstdint>
#include <cstddef>

#define N_SEQ 4096
#define D_HEAD 128
#define KP_DIM 256

typedef __attribute__((ext_vector_type(4))) float f32x4;
typedef __attribute__((ext_vector_type(8))) short bf16x8;
typedef __attribute__((ext_vector_type(4))) short s16x4;
typedef __attribute__((ext_vector_type(2))) unsigned int u32x2;

static __device__ __forceinline__ short f2bf(float f) {
  uint32_t u = __builtin_bit_cast(uint32_t, f);
  u += 0x7FFFu + ((u >> 16) & 1u);
  return (short)(u >> 16);
}

static __device__ __forceinline__ unsigned int cvtpk(float a, float b) {
  unsigned int r;
  asm("v_cvt_pk_bf16_f32 %0, %1, %2" : "=v"(r) : "v"(a), "v"(b));
  return r;
}

static __device__ __forceinline__ int swz8(int r) { return (r ^ (r >> 2)) & 7; }

// ---------------------------------------------------------------------------
// Stage 0: convert E_W,F_W f32 -> bf16 wbf[2][256][4096] (d_out scratch)
// ---------------------------------------------------------------------------
__global__ __launch_bounds__(256) void conv_w_kernel(
    const float* __restrict__ EW, const float* __restrict__ FW,
    short* __restrict__ wbf) {
  const int idx = blockIdx.x * 256 + threadIdx.x;
  const int half = 262144;
  f32x4 v = (idx < half) ? *(const f32x4*)(EW + (size_t)idx * 4)
                         : *(const f32x4*)(FW + (size_t)(idx - half) * 4);
  u32x2 h = {cvtpk(v[0], v[1]), cvtpk(v[2], v[3])};
  *(u32x2*)(wbf + (size_t)idx * 4) = h;
}

// ---------------------------------------------------------------------------
// Stage 1: partial projections (unchanged). grid 256, 512 thr.
// ---------------------------------------------------------------------------
__global__ __launch_bounds__(512) void proj_partial_kernel(
    const float* __restrict__ Kin, const float* __restrict__ Vin,
    const short* __restrict__ wbf, float* __restrict__ pws) {
  const int bid = blockIdx.x;
  const int wk = (bid & 7) * 32 + (bid >> 3);
  const int b = wk & 31;
  const int s = (wk >> 5) & 3;
  const int p = wk >> 7;

  const float* __restrict__ X = (p == 0 ? Kin : Vin) + (size_t)b * (N_SEQ * D_HEAD);
  const short* __restrict__ wp = wbf + (size_t)p * (KP_DIM * N_SEQ);
  float* __restrict__ outp = pws + ((((size_t)b * 2 + p) * 4) + s) * (KP_DIM * D_HEAD);

  __shared__ __align__(16) short lw[2][KP_DIM * 64];
  __shared__ __align__(16) short xt[2][D_HEAD * 64];

  const int t = threadIdx.x;
  const int lane = t & 63;
  const int w = t >> 6;
  const int wm = (w >> 1) * 64;
  const int wn = (w & 1) * 64;
  const int l15 = lane & 15;
  const int l4 = lane >> 4;
  const int dq = t & 31;
  const int ng = t >> 5;

  const int n0 = s * 1024;

  f32x4 acc[4][4];
#pragma unroll
  for (int i = 0; i < 4; ++i)
#pragma unroll
    for (int j = 0; j < 4; ++j) acc[i][j] = (f32x4){0.f, 0.f, 0.f, 0.f};

  f32x4 xreg[4];

#pragma unroll
  for (int i = 0; i < 4; ++i)
    xreg[i] = *(const f32x4*)(X + (size_t)(n0 + ng * 4 + i) * D_HEAD + dq * 4);
#pragma unroll
  for (int i = 0; i < 4; ++i) {
    int g = t + i * 512;
    int row = g >> 3, c = g & 7;
    __builtin_amdgcn_global_load_lds(
        (const __attribute__((address_space(1))) void*)(wp + (size_t)row * N_SEQ + n0 +
                                                        ((c ^ swz8(row)) << 3)),
        (__attribute__((address_space(3))) void*)(&lw[0][g * 8]), 16, 0, 0);
  }
  asm volatile("s_waitcnt vmcnt(4)" ::: "memory");
#pragma unroll
  for (int j = 0; j < 4; ++j) {
    int drow = dq * 4 + j;
    u32x2 hv = {cvtpk(xreg[0][j], xreg[1][j]), cvtpk(xreg[2][j], xreg[3][j])};
    *(u32x2*)(&xt[0][drow * 64 + ((ng * 4) ^ (swz8(drow) << 3))]) = hv;
  }
  asm volatile("s_waitcnt vmcnt(0)" ::: "memory");
  __syncthreads();

  for (int it = 0; it < 16; ++it) {
    const int cur = it & 1, nxt = cur ^ 1;
    if (it < 15) {
      const int nc = n0 + (it + 1) * 64;
#pragma unroll
      for (int i = 0; i < 4; ++i)
        xreg[i] = *(const f32x4*)(X + (size_t)(nc + ng * 4 + i) * D_HEAD + dq * 4);
#pragma unroll
      for (int i = 0; i < 4; ++i) {
        int g = t + i * 512;
        int row = g >> 3, c = g & 7;
        __builtin_amdgcn_global_load_lds(
            (const __attribute__((address_space(1))) void*)(wp + (size_t)row * N_SEQ + nc +
                                                            ((c ^ swz8(row)) << 3)),
            (__attribute__((address_space(3))) void*)(&lw[nxt][g * 8]), 16, 0, 0);
      }
    }
#pragma unroll
    for (int ks2 = 0; ks2 < 2; ++ks2) {
      const int col0 = ks2 * 32 + l4 * 8;
      bf16x8 a[4], bb[4];
#pragma unroll
      for (int mt = 0; mt < 4; ++mt) {
        int row = wm + mt * 16 + l15;
        a[mt] = *(const bf16x8*)(&lw[cur][row * 64 + (col0 ^ (swz8(row) << 3))]);
      }
#pragma unroll
      for (int nt = 0; nt < 4; ++nt) {
        int row = wn + nt * 16 + l15;
        bb[nt] = *(const bf16x8*)(&xt[cur][row * 64 + (col0 ^ (swz8(row) << 3))]);
      }
#pragma unroll
      for (int mt = 0; mt < 4; ++mt)
#pragma unroll
        for (int nt = 0; nt < 4; ++nt)
          acc[mt][nt] = __builtin_amdgcn_mfma_f32_16x16x32_bf16(a[mt], bb[nt], acc[mt][nt], 0, 0, 0);
    }
    if (it < 15) {
      asm volatile("s_waitcnt vmcnt(4)" ::: "memory");
#pragma unroll
      for (int j = 0; j < 4; ++j) {
        int drow = dq * 4 + j;
        u32x2 hv = {cvtpk(xreg[0][j], xreg[1][j]), cvtpk(xreg[2][j], xreg[3][j])};
        *(u32x2*)(&xt[nxt][drow * 64 + ((ng * 4) ^ (swz8(drow) << 3))]) = hv;
      }
      asm volatile("s_waitcnt vmcnt(0)" ::: "memory");
    }
    __syncthreads();
  }

#pragma unroll
  for (int mt = 0; mt < 4; ++mt)
#pragma unroll
    for (int nt = 0; nt < 4; ++nt)
#pragma unroll
      for (int r = 0; r < 4; ++r) {
        int kk = wm + mt * 16 + l4 * 4 + r;
        int dd = wn + nt * 16 + l15;
        outp[kk * D_HEAD + dd] = acc[mt][nt][r];
      }
}

// ---------------------------------------------------------------------------
// Stage 1b: reduce 4 partials + bias. grid 128.
// ---------------------------------------------------------------------------
__global__ __launch_bounds__(256) void reduce_bias_kernel(
    const float* __restrict__ pws, const float* __restrict__ Eb,
    const float* __restrict__ Fb, short* __restrict__ kp, short* __restrict__ vpt) {
  const int sub = blockIdx.x & 3;
  const int b = blockIdx.x >> 2;
  const int t = threadIdx.x;
  __shared__ short tile[128 * 128];
  if (sub < 2) {
    const float* __restrict__ base = pws + ((size_t)b * 2) * 4 * 32768;
    const int off = sub * 16384;
    for (int i = t; i < 16384; i += 256) {
      int ii = off + i;
      int k = ii >> 7;
      float v = base[ii] + base[ii + 32768] + base[ii + 65536] + base[ii + 98304] + Eb[k];
      kp[(size_t)b * 32768 + ii] = f2bf(v);
    }
  } else {
    const int kh = sub - 2;
    const float* __restrict__ base = pws + (((size_t)b * 2 + 1) * 4) * 32768 + kh * 16384;
    for (int i = t; i < 16384; i += 256) {
      int kl = i >> 7, d = i & 127;
      float v = base[i] + base[i + 32768] + base[i + 65536] + base[i + 98304] + Fb[kh * 128 + kl];
      tile[kl * 128 + (d ^ ((kl & 15) << 3))] = f2bf(v);
    }
    __syncthreads();
    for (int i = t; i < 16384; i += 256) {
      int d = i >> 7, kl = i & 127;
      vpt[(size_t)b * 32768 + d * 256 + kh * 128 + kl] = tile[kl * 128 + (d ^ ((kl & 15) << 3))];
    }
  }
}

// ---------------------------------------------------------------------------
// Stage 2: attention v4. grid 256 (XCD-chunked), 1024 thr = 16 waves,
// __launch_bounds__(1024,4) pins VGPR<=128 (4 waves/SIMD, NO spill).
// 16 rows/wave, 2 rounds of 256 rows. LDS 160KB: kp 64K + vpt 64K +
// dedicated per-wave P scratch 32K -> zero barriers after initial stage.
// PV transposed (mfma(av,pa)) -> coalesced f32x4 stores. Round-2 Q
// prefetched in round-1 PV tail.
// ---------------------------------------------------------------------------
__global__ __launch_bounds__(1024, 4) void attn_kernel(
    const float* __restrict__ Q, const short* __restrict__ kp,
    const short* __restrict__ vpt, float* __restrict__ out) {
  const int bid = blockIdx.x;
  const int wk = (bid & 7) * 32 + (bid >> 3);  // XCD-chunked: 4 b's per XCD
  const int b = wk >> 3;
  const int slice = wk & 7;
  const int t = threadIdx.x;
  const int lane = t & 63;
  const int w = t >> 6;  // 0..15
  const int l15 = lane & 15, l4 = lane >> 4;

  // 160KB LDS: lkp 64KB | lvpt 64KB | lp 32KB (16 waves x 2KB)
  __shared__ __align__(16) short lbuf[81920];
  short* lkp = lbuf;
  short* lvpt = lbuf + 32768;
  short* lpw = lbuf + 65536 + w * 1024;  // 2KB/wave: 16 rows x 128B

  const short* __restrict__ kpb = kp + (size_t)b * 32768;
  const short* __restrict__ vptb = vpt + (size_t)b * 32768;

  // ---- stage kp + vpt (linear LDS dest, swizzled source) ----
#pragma unroll
  for (int i = 0; i < 4; ++i) {
    int g = t + i * 1024;
    int row = g >> 4, c = g & 15;
    __builtin_amdgcn_global_load_lds(
        (const __attribute__((address_space(1))) void*)(kpb + (size_t)row * 128 +
                                                        ((c ^ (row & 7)) << 3)),
        (__attribute__((address_space(3))) void*)(&lkp[g * 8]), 16, 0, 0);
  }
#pragma unroll
  for (int i = 0; i < 4; ++i) {
    int g = t + i * 1024;
    int row = g >> 5, c = g & 31;
    __builtin_amdgcn_global_load_lds(
        (const __attribute__((address_space(1))) void*)(vptb + (size_t)row * 256 +
                                                        ((c ^ (row & 7)) << 3)),
        (__attribute__((address_space(3))) void*)(&lvpt[g * 8]), 16, 0, 0);
  }

  const float scale = 0.08838834764831845f;  // 1/sqrt(128)
  f32x4 qraw[8];
  {
    const float* qr = Q + ((size_t)b * N_SEQ + slice * 512 + w * 16 + l15) * D_HEAD;
#pragma unroll
    for (int ks = 0; ks < 4; ++ks) {
      qraw[2 * ks] = *(const f32x4*)(qr + ks * 32 + l4 * 8);
      qraw[2 * ks + 1] = *(const f32x4*)(qr + ks * 32 + l4 * 8 + 4);
    }
  }
  asm volatile("s_waitcnt vmcnt(0)" ::: "memory");
  __syncthreads();

#pragma unroll
  for (int rd = 0; rd < 2; ++rd) {
    const int rowBase = slice * 512 + rd * 256 + w * 16;

    // ---- convert current Q regs -> fragments (pre-scaled) ----
    bf16x8 qf[4];
#pragma unroll
    for (int ks = 0; ks < 4; ++ks) {
      union { unsigned int u[4]; bf16x8 v; } cv;
      cv.u[0] = cvtpk(qraw[2 * ks][0] * scale, qraw[2 * ks][1] * scale);
      cv.u[1] = cvtpk(qraw[2 * ks][2] * scale, qraw[2 * ks][3] * scale);
      cv.u[2] = cvtpk(qraw[2 * ks + 1][0] * scale, qraw[2 * ks + 1][1] * scale);
      cv.u[3] = cvtpk(qraw[2 * ks + 1][2] * scale, qraw[2 * ks + 1][3] * scale);
      qf[ks] = cv.v;
    }

    // ---- QK^T (swapped operands: lane owns q-row l15) ----
    f32x4 accs[16];
#pragma unroll
    for (int i = 0; i < 16; ++i) accs[i] = (f32x4){0.f, 0.f, 0.f, 0.f};
#pragma unroll
    for (int ks = 0; ks < 4; ++ks) {
#pragma unroll
      for (int nt = 0; nt < 16; ++nt) {
        bf16x8 af = *(const bf16x8*)(&lkp[(nt * 16 + l15) * 128 +
                                          (((ks * 4 + l4) ^ (l15 & 7)) << 3)]);
        accs[nt] = __builtin_amdgcn_mfma_f32_16x16x32_bf16(af, qf[ks], accs[nt], 0, 0, 0);
      }
    }

    // ---- softmax (2 shuffles) ----
    float m = -1e30f;
#pragma unroll
    for (int nt = 0; nt < 16; ++nt)
#pragma unroll
      for (int r = 0; r < 4; ++r) m = fmaxf(m, accs[nt][r]);
    m = fmaxf(m, __shfl_xor(m, 16));
    m = fmaxf(m, __shfl_xor(m, 32));
    float s = 0.f;
#pragma unroll
    for (int nt = 0; nt < 16; ++nt)
#pragma unroll
      for (int r = 0; r < 4; ++r) {
        float e = __expf(accs[nt][r] - m);
        accs[nt][r] = e;
        s += e;
      }
    s += __shfl_xor(s, 16);
    s += __shfl_xor(s, 32);
    float inv = 1.0f / s;

    // ---- PV via per-wave P scratch; transposed MFMA; acco[d][n] ----
    f32x4 acco[8];
#pragma unroll
    for (int i = 0; i < 8; ++i) acco[i] = (f32x4){0.f, 0.f, 0.f, 0.f};
#pragma unroll
    for (int qq = 0; qq < 4; ++qq) {
#pragma unroll
      for (int ntl = 0; ntl < 4; ++ntl) {
        int nt = qq * 4 + ntl;
        int cw = 2 * ntl + (l4 >> 1);
        unsigned int p0 = cvtpk(accs[nt][0] * inv, accs[nt][1] * inv);
        unsigned int p1 = cvtpk(accs[nt][2] * inv, accs[nt][3] * inv);
        *(u32x2*)((char*)lpw + l15 * 128 + ((cw ^ (l15 & 7)) << 4) + (l4 & 1) * 8) =
            (u32x2){p0, p1};
      }
      if (rd == 0 && qq == 3) {
        // prefetch round-2 Q (accs mostly dead here)
        const float* qr = Q + ((size_t)b * N_SEQ + slice * 512 + 256 + w * 16 + l15) * D_HEAD;
#pragma unroll
        for (int ks = 0; ks < 4; ++ks) {
          qraw[2 * ks] = *(const f32x4*)(qr + ks * 32 + l4 * 8);
          qraw[2 * ks + 1] = *(const f32x4*)(qr + ks * 32 + l4 * 8 + 4);
        }
      }
#pragma unroll
      for (int ksl = 0; ksl < 2; ++ksl) {
        bf16x8 pa = *(const bf16x8*)((char*)lpw + l15 * 128 +
                                     (((4 * ksl + l4) ^ (l15 & 7)) << 4));
        int ksa = qq * 2 + ksl;
#pragma unroll
        for (int ntv = 0; ntv < 8; ++ntv) {
          bf16x8 av = *(const bf16x8*)(&lvpt[(ntv * 16 + l15) * 256 +
                                             (((ksa * 4 + l4) ^ (l15 & 7)) << 3)]);
          acco[ntv] = __builtin_amdgcn_mfma_f32_16x16x32_bf16(av, pa, acco[ntv], 0, 0, 0);
        }
      }
    }

    // ---- coalesced stores: lane writes 4 consecutive d for its q-row ----
    float* ob = out + ((size_t)b * N_SEQ + rowBase) * D_HEAD;
#pragma unroll
    for (int ntv = 0; ntv < 8; ++ntv)
      *(f32x4*)(ob + (size_t)l15 * D_HEAD + ntv * 16 + l4 * 4) = acco[ntv];
  }
}

// ---------------------------------------------------------------------------
extern "C" void kernel_launch(void* const* d_in, const int* in_sizes, int n_in,
                              void* d_out, int out_size, void* d_ws, size_t ws_size,
                              hipStream_t stream) {
  const float* Q  = (const float*)d_in[0];
  const float* K  = (const float*)d_in[1];
  const float* V  = (const float*)d_in[2];
  const float* EW = (const float*)d_in[3];
  const float* Eb = (const float*)d_in[4];
  const float* FW = (const float*)d_in[5];
  const float* Fb = (const float*)d_in[6];
  float* out = (float*)d_out;

  // d_out scratch (dead before attn writes): [0,4MB) wbf; [8MB,41.5MB) pws
  short* wbf = (short*)d_out;
  float* pws = (float*)d_out + 2097152;
  short* kpb = (short*)d_ws;
  short* vpt = (short*)((char*)d_ws + (size_t)32 * KP_DIM * D_HEAD * 2);

  conv_w_kernel<<<dim3(2048), dim3(256), 0, stream>>>(EW, FW, wbf);
  proj_partial_kernel<<<dim3(256), dim3(512), 0, stream>>>(K, V, wbf, pws);
  reduce_bias_kernel<<<dim3(128), dim3(256), 0, stream>>>(pws, Eb, Fb, kpb, vpt);
  attn_kernel<<<dim3(256), dim3(1024), 0, stream>>>(Q, kpb, vpt, out);
}